// Round 1
// baseline (24858.499 us; speedup 1.0000x reference)
//
#include <hip/hip_runtime.h>
#include <hip/hip_bf16.h>
#include <stdint.h>

#define Bn 64
#define Tn 512
#define Hn 1024
#define Ln 4
#define GN 4096   // 4*H

typedef __attribute__((ext_vector_type(8))) short bf16x8;
typedef __attribute__((ext_vector_type(4))) float f32x4;
typedef __attribute__((ext_vector_type(4))) unsigned short u16x4;

__device__ __forceinline__ unsigned short f2bf(float f) {
  union { float f; unsigned u; } v; v.f = f;
  return (unsigned short)((v.u + 0x7FFFu + ((v.u >> 16) & 1u)) >> 16);
}

__device__ __forceinline__ void gload16(const void* g, void* l) {
  __builtin_amdgcn_global_load_lds((const __attribute__((address_space(1))) void*)g,
                                   (__attribute__((address_space(3))) void*)l, 16, 0, 0);
}

__device__ __forceinline__ float sigmf(float x) { return 1.0f / (1.0f + expf(-x)); }

// ---------------- prep: lengths + stable descending rank ----------------
__global__ void prep_kernel(const int* __restrict__ x, int* __restrict__ len, int* __restrict__ rank) {
  __shared__ int sl[Bn];
  int b = threadIdx.x;
  if (b < Bn) {
    int cnt = 0;
    const int* row = x + (size_t)b * Tn;
    for (int t = 0; t < Tn; ++t) cnt += (row[t] > 0) ? 1 : 0;
    sl[b] = cnt;
  }
  __syncthreads();
  if (b < Bn) {
    int Lb = sl[b], r = 0;
    for (int j = 0; j < Bn; ++j) {
      int lj = sl[j];
      r += ((lj > Lb) || (lj == Lb && j < b)) ? 1 : 0;
    }
    len[b] = Lb;
    rank[b] = r;
  }
}

// ---------------- bias fold: b_ih + b_hh ----------------
__global__ void bias_kernel(const float* __restrict__ bih, const float* __restrict__ bhh,
                            float* __restrict__ bias) {
  int i = blockIdx.x * blockDim.x + threadIdx.x; // 16384
  if (i < Ln * GN) bias[i] = bih[i] + bhh[i];
}

// ---------------- cast weights f32 -> bf16 ----------------
__global__ __launch_bounds__(256) void cast_w_kernel(const float* __restrict__ Wih,
                                                     const float* __restrict__ Whh,
                                                     unsigned short* __restrict__ WihB,
                                                     unsigned short* __restrict__ WhhB) {
  size_t i = (size_t)blockIdx.x * blockDim.x + threadIdx.x; // 4194304 float4 groups
  if (i >= (size_t)Ln * GN * Hn / 4) return;
  f32x4 a = ((const f32x4*)Wih)[i];
  f32x4 b = ((const f32x4*)Whh)[i];
  u16x4 pa, pb;
#pragma unroll
  for (int u = 0; u < 4; ++u) { pa[u] = f2bf(a[u]); pb[u] = f2bf(b[u]); }
  ((u16x4*)WihB)[i] = pa;
  ((u16x4*)WhhB)[i] = pb;
}

// ---------------- embedding gather -> Xbuf (T,B,H) bf16 ----------------
__global__ __launch_bounds__(256) void embed_kernel(const int* __restrict__ x,
                                                    const float* __restrict__ emb,
                                                    unsigned short* __restrict__ Xbuf) {
  int row = blockIdx.x;        // t*64 + b
  int t = row >> 6, b = row & 63;
  int tok = x[(size_t)b * Tn + t];
  f32x4 v = ((const f32x4*)(emb + (size_t)tok * Hn))[threadIdx.x];
  u16x4 p;
#pragma unroll
  for (int u = 0; u < 4; ++u) p[u] = f2bf(v[u]);
  ((u16x4*)(Xbuf + (size_t)row * Hn))[threadIdx.x] = p;
}

// ---------------- init per-layer state ----------------
__global__ void init_state_kernel(const float* __restrict__ h0l, const float* __restrict__ c0l,
                                  unsigned short* __restrict__ hbf0,
                                  float* __restrict__ hf32, float* __restrict__ cst) {
  int i = blockIdx.x * blockDim.x + threadIdx.x; // 65536
  float h = h0l[i], c = c0l[i];
  hf32[i] = h; cst[i] = c; hbf0[i] = f2bf(h);
}

// ---------------- big input GEMM: G = A(M,K)bf16 @ W(N,K)bf16^T + bias, f32 out ----------------
// grid: (32, M/128), block 256 (4 waves, 2x2), tile 128x128, BK=64, XOR-swizzled LDS
__global__ __launch_bounds__(256) void gemm_in_kernel(const char* __restrict__ Abf,
                                                      const char* __restrict__ Wbf,
                                                      const float* __restrict__ bias,
                                                      float* __restrict__ Gout) {
  __shared__ char smem[32768]; // As[128][128B] , Bs[128][128B]
  int tid = threadIdx.x;
  int bn = blockIdx.x, bm = blockIdx.y;
  int wave = tid >> 6, lane = tid & 63, l15 = lane & 15, lk = lane >> 4;
  int wm = wave >> 1, wn = wave & 1;
  f32x4 acc[4][4] = {};

  for (int kk = 0; kk < 16; ++kk) {
#pragma unroll
    for (int i = 0; i < 8; ++i) {
      int o = i * 4096 + tid * 16;
      int local = o & 16383;
      int row = local >> 7;
      int within = local & 127;
      int kb = within ^ ((row & 7) << 4);   // pre-swizzled source (T2 both-sides rule)
      const char* src;
      if (o < 16384) src = Abf + (size_t)(bm * 128 + row) * 2048 + kk * 128 + kb;
      else           src = Wbf + (size_t)(bn * 128 + row) * 2048 + kk * 128 + kb;
      gload16(src, smem + o);
    }
    __syncthreads();
#pragma unroll
    for (int ks = 0; ks < 2; ++ks) {
      int kb = ks * 64 + lk * 16;
      bf16x8 af[4], bfv[4];
#pragma unroll
      for (int mi = 0; mi < 4; ++mi) {
        int row = wm * 64 + mi * 16 + l15;
        af[mi] = *(const bf16x8*)(smem + row * 128 + (kb ^ ((row & 7) << 4)));
      }
#pragma unroll
      for (int ni = 0; ni < 4; ++ni) {
        int row = wn * 64 + ni * 16 + l15;
        bfv[ni] = *(const bf16x8*)(smem + 16384 + row * 128 + (kb ^ ((row & 7) << 4)));
      }
#pragma unroll
      for (int mi = 0; mi < 4; ++mi)
#pragma unroll
        for (int ni = 0; ni < 4; ++ni)
          acc[mi][ni] = __builtin_amdgcn_mfma_f32_16x16x32_bf16(af[mi], bfv[ni], acc[mi][ni], 0, 0, 0);
    }
    __syncthreads();
  }
  float bv[4];
#pragma unroll
  for (int ni = 0; ni < 4; ++ni) bv[ni] = bias[bn * 128 + wn * 64 + ni * 16 + l15];
#pragma unroll
  for (int mi = 0; mi < 4; ++mi)
#pragma unroll
    for (int ni = 0; ni < 4; ++ni)
#pragma unroll
      for (int j = 0; j < 4; ++j) {
        int row = bm * 128 + wm * 64 + mi * 16 + lk * 4 + j;  // C/D: col=lane&15, row=(lane>>4)*4+j
        int col = bn * 128 + wn * 64 + ni * 16 + l15;
        Gout[(size_t)row * GN + col] = acc[mi][ni][j] + bv[ni];
      }
}

// ---------------- recurrent step: gates = G[t] + h@Whh^T; fused LSTM cell ----------------
// grid 64 blocks (16 h-cols each), 256 threads (wave w = gate w). BK=128 elems (256B rows).
__global__ __launch_bounds__(256) void lstm_step_kernel(
    const char* __restrict__ hbf_r, unsigned short* __restrict__ hbf_w,
    const char* __restrict__ WhhL, const float* __restrict__ Gt,
    float* __restrict__ hf32, float* __restrict__ cst,
    const int* __restrict__ len, unsigned short* __restrict__ Xnext,
    float* __restrict__ outp, int t, int isLast) {
  __shared__ char smem[32768]; // As[64][256B] + Bs[64][256B]
  int tid = threadIdx.x, bn = blockIdx.x;
  int w = tid >> 6, lane = tid & 63, l15 = lane & 15, lk = lane >> 4;
  f32x4 acc[4] = {};

  for (int kk = 0; kk < 8; ++kk) {
#pragma unroll
    for (int i = 0; i < 8; ++i) {
      int o = i * 4096 + tid * 16;
      int local = o & 16383;
      int row = local >> 8;
      int within = local & 255;
      int kb = within ^ ((row & 15) << 4);
      const char* src;
      if (o < 16384) {
        src = hbf_r + (size_t)row * 2048 + kk * 256 + kb;
      } else {
        int gid = ((row >> 4) << 10) + bn * 16 + (row & 15); // gate strip rows of Whh
        src = WhhL + (size_t)gid * 2048 + kk * 256 + kb;
      }
      gload16(src, smem + o);
    }
    __syncthreads();
#pragma unroll
    for (int ks = 0; ks < 4; ++ks) {
      int kb = ks * 64 + lk * 16;
      int brow = w * 16 + l15;
      bf16x8 bfr = *(const bf16x8*)(smem + 16384 + brow * 256 + (kb ^ ((brow & 15) << 4)));
#pragma unroll
      for (int mi = 0; mi < 4; ++mi) {
        int arow = mi * 16 + l15;
        bf16x8 afr = *(const bf16x8*)(smem + arow * 256 + (kb ^ ((arow & 15) << 4)));
        acc[mi] = __builtin_amdgcn_mfma_f32_16x16x32_bf16(afr, bfr, acc[mi], 0, 0, 0);
      }
    }
    __syncthreads();
  }
  // exchange gate strips through LDS: SM[gate][64][16] f32 (reuses As region)
  float* smf = (float*)smem;
#pragma unroll
  for (int mi = 0; mi < 4; ++mi)
#pragma unroll
    for (int j = 0; j < 4; ++j)
      smf[w * 1024 + (mi * 16 + lk * 4 + j) * 16 + l15] = acc[mi][j];
  __syncthreads();

  int r = tid >> 2;
  int c0 = (tid & 3) << 2;
  int hc = bn * 16 + c0;
  const float* Grow = Gt + (size_t)r * GN;
  f32x4 gI = *(const f32x4*)(Grow + hc);
  f32x4 gF = *(const f32x4*)(Grow + 1024 + hc);
  f32x4 gG = *(const f32x4*)(Grow + 2048 + hc);
  f32x4 gO = *(const f32x4*)(Grow + 3072 + hc);
  f32x4 sI = *(const f32x4*)(smf + r * 16 + c0);
  f32x4 sF = *(const f32x4*)(smf + 1024 + r * 16 + c0);
  f32x4 sG = *(const f32x4*)(smf + 2048 + r * 16 + c0);
  f32x4 sO = *(const f32x4*)(smf + 3072 + r * 16 + c0);
  f32x4 cold = *(const f32x4*)(cst + (size_t)r * Hn + hc);
  f32x4 hold = *(const f32x4*)(hf32 + (size_t)r * Hn + hc);
  bool msk = (t < len[r]);
  f32x4 cn, hn, hx;
#pragma unroll
  for (int u = 0; u < 4; ++u) {
    float iv = sigmf(gI[u] + sI[u]);
    float fv = sigmf(gF[u] + sF[u]);
    float gv = tanhf(gG[u] + sG[u]);
    float ov = sigmf(gO[u] + sO[u]);
    float cc = fv * cold[u] + iv * gv;
    float hh = ov * tanhf(cc);
    hx[u] = hh;                      // fresh h (fed to next layer; masked rows irrelevant downstream)
    cn[u] = msk ? cc : cold[u];      // frozen state semantics
    hn[u] = msk ? hh : hold[u];
  }
  *(f32x4*)(cst + (size_t)r * Hn + hc) = cn;
  *(f32x4*)(hf32 + (size_t)r * Hn + hc) = hn;
  u16x4 hb, xb;
#pragma unroll
  for (int u = 0; u < 4; ++u) { hb[u] = f2bf(hn[u]); xb[u] = f2bf(hx[u]); }
  *(u16x4*)(hbf_w + (size_t)r * Hn + hc) = hb;   // always write: carries frozen value forward
  *(u16x4*)(Xnext + (size_t)r * Hn + hc) = xb;
  if (isLast) {
    f32x4 o4;
#pragma unroll
    for (int u = 0; u < 4; ++u) o4[u] = msk ? hx[u] : 0.0f;
    *(f32x4*)(outp + ((size_t)r * Tn + t) * Hn + hc) = o4;
  }
}

// ---------------- final state writeback with rank permutation ----------------
__global__ void finalize_kernel(const float* __restrict__ hf32, const float* __restrict__ cst,
                                const int* __restrict__ rank,
                                float* __restrict__ hF, float* __restrict__ cF) {
  int i = blockIdx.x * blockDim.x + threadIdx.x; // 65536? launched grid-stride capable
  for (; i < Bn * Hn; i += gridDim.x * blockDim.x) {
    int b = i >> 10, k = i & 1023;
    int rb = rank[b];
    hF[(size_t)rb * Hn + k] = hf32[i];
    cF[(size_t)rb * Hn + k] = cst[i];
  }
}

extern "C" void kernel_launch(void* const* d_in, const int* in_sizes, int n_in,
                              void* d_out, int out_size, void* d_ws, size_t ws_size,
                              hipStream_t stream) {
  const int*   x   = (const int*)d_in[0];
  const float* h0  = (const float*)d_in[1];
  const float* c0  = (const float*)d_in[2];
  const float* emb = (const float*)d_in[3];
  const float* Wih = (const float*)d_in[4];
  const float* Whh = (const float*)d_in[5];
  const float* bih = (const float*)d_in[6];
  const float* bhh = (const float*)d_in[7];
  float* out = (float*)d_out;

  char* ws = (char*)d_ws;
  unsigned short* WihB = (unsigned short*)ws;                  // 33554432 B
  unsigned short* WhhB = (unsigned short*)(ws + 33554432);     // 33554432 B
  float* biasF = (float*)(ws + 67108864);                      // 65536 B
  unsigned short* Xbuf = (unsigned short*)(ws + 67174400);     // 67108864 B
  unsigned short* hbf0 = (unsigned short*)(ws + 134283264);    // 131072 B
  unsigned short* hbf1 = (unsigned short*)(ws + 134414336);    // 131072 B
  float* hf32v = (float*)(ws + 134545408);                     // 262144 B
  float* cstv  = (float*)(ws + 134807552);                     // 262144 B
  int* leni  = (int*)(ws + 135069696);
  int* ranki = (int*)(ws + 135069952);
  float* Gbuf = (float*)(ws + 135070208);
  const size_t GOFF = 135070208;

  // pick largest time-chunk Tc whose f32 gate buffer fits the workspace
  int Tc = 8;
  const int cands[7] = {512, 256, 128, 64, 32, 16, 8};
  for (int ci = 0; ci < 7; ++ci) {
    if (GOFF + (size_t)cands[ci] * (size_t)Bn * GN * 4 <= ws_size) { Tc = cands[ci]; break; }
  }
  int nch = Tn / Tc;

  prep_kernel<<<1, 64, 0, stream>>>(x, leni, ranki);
  bias_kernel<<<64, 256, 0, stream>>>(bih, bhh, biasF);
  cast_w_kernel<<<16384, 256, 0, stream>>>(Wih, Whh, WihB, WhhB);
  embed_kernel<<<Tn * Bn, 256, 0, stream>>>(x, emb, Xbuf);

  float* hFbase = out + (size_t)Bn * Tn * Hn;
  float* cFbase = hFbase + (size_t)Ln * Bn * Hn;

  for (int l = 0; l < Ln; ++l) {
    init_state_kernel<<<256, 256, 0, stream>>>(h0 + (size_t)l * Bn * Hn, c0 + (size_t)l * Bn * Hn,
                                               hbf0, hf32v, cstv);
    const char* WihL = (const char*)WihB + (size_t)l * GN * Hn * 2;
    const char* WhhL = (const char*)WhhB + (size_t)l * GN * Hn * 2;
    for (int ch = 0; ch < nch; ++ch) {
      const char* Achunk = (const char*)Xbuf + (size_t)ch * Tc * Bn * Hn * 2;
      gemm_in_kernel<<<dim3(32, Tc * Bn / 128), 256, 0, stream>>>(Achunk, WihL, biasF + l * GN, Gbuf);
      for (int tr = 0; tr < Tc; ++tr) {
        int t = ch * Tc + tr;
        const char* hbR = (const char*)((t & 1) ? hbf1 : hbf0);
        unsigned short* hbW = (t & 1) ? hbf0 : hbf1;
        lstm_step_kernel<<<64, 256, 0, stream>>>(
            hbR, hbW, WhhL, Gbuf + (size_t)tr * Bn * GN,
            hf32v, cstv, leni, Xbuf + (size_t)t * Bn * Hn,
            out, t, (l == Ln - 1) ? 1 : 0);
      }
    }
    finalize_kernel<<<64, 256, 0, stream>>>(hf32v, cstv, ranki,
                                            hFbase + (size_t)l * Bn * Hn,
                                            cFbase + (size_t)l * Bn * Hn);
  }
}